// Round 4
// baseline (645.516 us; speedup 1.0000x reference)
//
#include <hip/hip_runtime.h>
#include <hip/hip_bf16.h>

// Shapes (fixed by reference): B=32, T=2048, H=1024, U=1024.
// out = [context (32*1024)][attention_weights (32*2048)]  (fp32)
// V_b is a uniform score shift -> cancels in softmax -> unused.

#define B_DIM 32
#define T_DIM 2048
#define H_DIM 1024
#define U_DIM 1024

typedef __bf16 bf16x8 __attribute__((ext_vector_type(8)));
typedef float f32x4 __attribute__((ext_vector_type(4)));

__device__ __forceinline__ unsigned int f2bf(float f) {
    unsigned int u = __float_as_uint(f);
    return (u + 0x7FFFu + ((u >> 16) & 1u)) >> 16;   // RNE
}

__device__ __forceinline__ unsigned int cvt2(float lo, float hi) {
    unsigned int r;
    asm volatile("v_cvt_pk_bf16_f32 %0, %1, %2" : "=v"(r) : "v"(lo), "v"(hi));
    return r;   // RNE packed pair, low half = lo
}

__device__ __forceinline__ float fast_tanh(float x) {
    x = fminf(9.f, fmaxf(-9.f, x));
    float e = __expf(2.f * x);
    return 1.f - 2.f * __frcp_rn(e + 1.f);
}

__device__ __forceinline__ void glds16(const void* g, const void* l) {
    __builtin_amdgcn_global_load_lds(
        (const __attribute__((address_space(1))) unsigned int*)g,
        (__attribute__((address_space(3))) unsigned int*)l, 16, 0, 0);
}

// ---------- pass 0a: Wv (first H cols of W_w rows) -> bf16, natural [u][k] ----------
__global__ void prep_wv_kernel(const float* __restrict__ W_w,
                               unsigned short* __restrict__ wv) {
    int u = blockIdx.x;            // 1024
    int tid = threadIdx.x;         // 256
    float4 x = reinterpret_cast<const float4*>(W_w + (size_t)u * 2 * H_DIM)[tid];
    uint2 p;
    p.x = f2bf(x.x) | (f2bf(x.y) << 16);
    p.y = f2bf(x.z) | (f2bf(x.w) << 16);
    reinterpret_cast<uint2*>(wv)[(size_t)u * (H_DIM / 4) + tid] = p;
}

// ---------- pass 0b: c[b][u] = q[b] . Wq[u] + W_b[u]  (fp32 exact) + zero ctx ----------
__global__ void prep_c_kernel(const float* __restrict__ q,     // [B][H]
                              const float* __restrict__ W_w,   // [U][2H]
                              const float* __restrict__ W_b,   // [U]
                              float* __restrict__ cvec,        // [B][U]
                              float* __restrict__ ctx) {       // [B][H] -> zeroed here
    __shared__ float4 q_sh[4][H_DIM / 4];     // 16 KB
    int bg = blockIdx.y;           // batch group: batches bg*4 .. bg*4+3
    int u0 = blockIdx.x * 64;
    int tid = threadIdx.x;
    int lane = tid & 63, w = tid >> 6;
    ctx[(size_t)(blockIdx.y * 16 + blockIdx.x) * 256 + tid] = 0.f;
#pragma unroll
    for (int i = 0; i < 4; i++)
        q_sh[i][tid] = reinterpret_cast<const float4*>(
            q + (size_t)(bg * 4 + i) * H_DIM)[tid];
    __syncthreads();
#pragma unroll
    for (int i = 0; i < 16; i++) {
        int u = u0 + w * 16 + i;
        const float4* wr = reinterpret_cast<const float4*>(W_w + (size_t)u * 2 * H_DIM + H_DIM);
        float s0 = 0.f, s1 = 0.f, s2 = 0.f, s3 = 0.f;
#pragma unroll
        for (int j = 0; j < 4; j++) {
            float4 wv4 = wr[j * 64 + lane];
            float4 qa = q_sh[0][j * 64 + lane];
            float4 qb = q_sh[1][j * 64 + lane];
            float4 qc = q_sh[2][j * 64 + lane];
            float4 qd = q_sh[3][j * 64 + lane];
            s0 += wv4.x * qa.x + wv4.y * qa.y + wv4.z * qa.z + wv4.w * qa.w;
            s1 += wv4.x * qb.x + wv4.y * qb.y + wv4.z * qb.z + wv4.w * qb.w;
            s2 += wv4.x * qc.x + wv4.y * qc.y + wv4.z * qc.z + wv4.w * qc.w;
            s3 += wv4.x * qd.x + wv4.y * qd.y + wv4.z * qd.z + wv4.w * qd.w;
        }
#pragma unroll
        for (int off = 32; off >= 1; off >>= 1) {
            s0 += __shfl_xor(s0, off, 64);
            s1 += __shfl_xor(s1, off, 64);
            s2 += __shfl_xor(s2, off, 64);
            s3 += __shfl_xor(s3, off, 64);
        }
        if (lane == 0) {
            float bb = W_b[u];
            cvec[(size_t)(bg * 4 + 0) * U_DIM + u] = s0 + bb;
            cvec[(size_t)(bg * 4 + 1) * U_DIM + u] = s1 + bb;
            cvec[(size_t)(bg * 4 + 2) * U_DIM + u] = s2 + bb;
            cvec[(size_t)(bg * 4 + 3) * U_DIM + u] = s3 + bb;
        }
    }
}

// ---------- pass 1: GEMM(values, Wv^T) + tanh + dot(V_w) -> partial score ----------
// 256(M) x 256(N), BK=32, 32 K-steps, 8 waves (2x4), wave tile 128x64.
// DEPTH-3 mod-3 LDS rotation, pure glds staging (A fp32, B bf16), ONE barrier
// per step, counted vmcnt(6) -- tile t's loads issued 2 full steps before use.
//   A LDS: [3][256 rows][128B fp32], slot(16B) ^= row&7  (zero-conflict layout)
//   B LDS: [3][128 prow][128B bf16], slot = ((r&1)*4+quad) ^ (prow&7)
// Swizzle is baked into per-lane glds SOURCE addresses; LDS dest stays linear.
// A converted fp32->bf16 at fragment-read time (cvt_pk), no staging regs.
__global__ __launch_bounds__(512, 2)
void gemm_score_kernel(const float* __restrict__ values,        // [B*T][H]
                       const unsigned short* __restrict__ wv,   // bf16 [U][H]
                       const float* __restrict__ cvec,          // [B][U]
                       const float* __restrict__ Vw,            // [U]
                       float* __restrict__ score_part) {        // [4][B*T]
    __shared__ __align__(16) float a_sh[3][256 * 32];            // 3 x 32 KB
    __shared__ __align__(16) unsigned short b_sh[3][128 * 64];   // 3 x 16 KB

    const int tid = threadIdx.x;
    const int lane = tid & 63;
    const int w = tid >> 6;          // wave 0..7
    const int col = lane & 15;
    const int quad = lane >> 4;
    const int wr = w >> 2;           // 0..1 (M half)
    const int wc = w & 3;            // 0..3 (N quarter)

    // XCD-chunked bijective swizzle (1024 % 8 == 0)
    const int work = (blockIdx.x & 7) * 128 + (blockIdx.x >> 3);
    const int mtile = work >> 2;     // 0..255
    const int ntile = work & 3;      // 0..3
    const int m0 = mtile * 256;
    const int b = m0 >> 11;

    f32x4 acc[8][4];
    const f32x4 zero4 = {0.f, 0.f, 0.f, 0.f};
#pragma unroll
    for (int mt = 0; mt < 8; mt++)
#pragma unroll
        for (int nt = 0; nt < 4; nt++) acc[mt][nt] = zero4;

    // glds source addressing (per-lane, swizzle pre-applied)
    const int l8 = lane >> 3, l7 = lane & 7;
    const int xa = l7 ^ l8;                      // A slot source / B combined idx
    const char* asrc = (const char*)values +
        (size_t)(m0 + w * 32 + l8) * 4096 + xa * 16;
    const char* bsrc = (const char*)wv +
        (size_t)((size_t)ntile * 256 + w * 32 + 2 * l8 + (xa >> 2)) * 2048 +
        (xa & 3) * 16;

    // fragment read byte offsets (within a buffer)
    const int aoff = (wr * 128 + col) * 128 + (((quad * 2) ^ (col & 7)) * 16);
    const int boff = (wc * 32 + (col >> 1)) * 128 +
                     (((((col & 1) << 2) | quad) ^ (col >> 1)) * 16);

#define STAGE(SBUF, KS) do {                                                   \
        glds16(asrc + (size_t)(KS) * 128,          &a_sh[SBUF][(w * 32) * 32]);      \
        glds16(asrc + (size_t)(KS) * 128 + 32768,  &a_sh[SBUF][(w * 32 + 8) * 32]);  \
        glds16(asrc + (size_t)(KS) * 128 + 65536,  &a_sh[SBUF][(w * 32 + 16) * 32]); \
        glds16(asrc + (size_t)(KS) * 128 + 98304,  &a_sh[SBUF][(w * 32 + 24) * 32]); \
        glds16(bsrc + (size_t)(KS) * 64,           &b_sh[SBUF][(w * 16) * 64]);      \
        glds16(bsrc + (size_t)(KS) * 64 + 32768,   &b_sh[SBUF][(w * 16 + 8) * 64]);  \
    } while (0)

#define KSTEP(BUF, VM, STG, SBUF, KS) do {                                     \
        asm volatile("s_waitcnt vmcnt(" #VM ")" ::: "memory");                 \
        __builtin_amdgcn_s_barrier();                                          \
        asm volatile("" ::: "memory");                                         \
        if (STG) STAGE(SBUF, KS);                                              \
        bf16x8 af[8], bf[4];                                                   \
        const char* ab_ = (const char*)&a_sh[BUF][0];                          \
        const char* bb_ = (const char*)&b_sh[BUF][0];                          \
        _Pragma("unroll")                                                      \
        for (int mt = 0; mt < 8; mt++) {                                       \
            int o0 = aoff + mt * 2048;                                         \
            float4 f0 = *reinterpret_cast<const float4*>(ab_ + o0);            \
            float4 f1 = *reinterpret_cast<const float4*>(ab_ + (o0 ^ 16));     \
            uint4 u_;                                                          \
            u_.x = cvt2(f0.x, f0.y); u_.y = cvt2(f0.z, f0.w);                  \
            u_.z = cvt2(f1.x, f1.y); u_.w = cvt2(f1.z, f1.w);                  \
            af[mt] = __builtin_bit_cast(bf16x8, u_);                           \
        }                                                                      \
        _Pragma("unroll")                                                      \
        for (int nt = 0; nt < 4; nt++)                                         \
            bf[nt] = *reinterpret_cast<const bf16x8*>(bb_ + boff + nt * 1024); \
        __builtin_amdgcn_s_setprio(1);                                         \
        _Pragma("unroll")                                                      \
        for (int nt = 0; nt < 4; nt++)                                         \
            _Pragma("unroll")                                                  \
            for (int mt = 0; mt < 8; mt++)                                     \
                acc[mt][nt] = __builtin_amdgcn_mfma_f32_16x16x32_bf16(         \
                    af[mt], bf[nt], acc[mt][nt], 0, 0, 0);                     \
        __builtin_amdgcn_s_setprio(0);                                         \
    } while (0)

    // prologue: tiles 0 and 1 in flight (6 glds each, oldest-first)
    STAGE(0, 0);
    STAGE(1, 1);

    // steps 0..29: uniform vmcnt(6) (retire tile t; t+1,t+2 stay in flight),
    // stage tile t+2 into buffer (t+2)%3.
    for (int t3 = 0; t3 < 30; t3 += 3) {
        KSTEP(0, 6, 1, 2, t3 + 2);
        KSTEP(1, 6, 1, 0, t3 + 3);
        KSTEP(2, 6, 1, 1, t3 + 4);
    }
    // step 30 (buf 0): nothing to stage; tile 31 still in flight
    KSTEP(0, 6, 0, 0, 0);
    // step 31 (buf 1): final drain
    KSTEP(1, 0, 0, 0, 0);

    __syncthreads();

#undef STAGE
#undef KSTEP

    // ---- epilogue: partial score over this block's 256 u-cols ----
    float* sc = reinterpret_cast<float*>(a_sh);   // reuse LDS
    float cv[4], vwv[4];
#pragma unroll
    for (int nt = 0; nt < 4; nt++) {
        int n = ntile * 256 + wc * 64 + nt * 16 + col;
        cv[nt] = cvec[(size_t)b * U_DIM + n];
        vwv[nt] = Vw[n];
    }
#pragma unroll
    for (int mt = 0; mt < 8; mt++) {
#pragma unroll
        for (int j = 0; j < 4; j++) {
            float s = 0.f;
#pragma unroll
            for (int nt = 0; nt < 4; nt++)
                s += fast_tanh(acc[mt][nt][j] + cv[nt]) * vwv[nt];
            s += __shfl_xor(s, 1, 64);
            s += __shfl_xor(s, 2, 64);
            s += __shfl_xor(s, 4, 64);
            s += __shfl_xor(s, 8, 64);
            if (col == 0) sc[(wr * 128 + mt * 16 + quad * 4 + j) * 4 + wc] = s;
        }
    }
    __syncthreads();
    if (tid < 256) {
        float s = sc[tid * 4] + sc[tid * 4 + 1] + sc[tid * 4 + 2] + sc[tid * 4 + 3];
        score_part[(size_t)ntile * (B_DIM * T_DIM) + m0 + tid] = s;
    }
}

// ---------- pass 2: fused softmax + context partial + atomic combine ----------
// grid (32, 32), 256 threads; 64-t chunks -> 1024 blocks (4/CU) for BW.
__global__ void ctx_sm_kernel(const float* __restrict__ values,
                              const float* __restrict__ score_part,  // [4][B*T]
                              float* __restrict__ aw,                // [B][T]
                              float* __restrict__ ctx) {             // [B][H]
    int tc = blockIdx.x;           // 32 chunks of 64 t
    int b = blockIdx.y;            // 32
    int tid = threadIdx.x;         // 256
    int lane = tid & 63, w = tid >> 6;
    __shared__ float redm[4];
    __shared__ float reds[4];
    __shared__ float aw_sh[64];
    const float* sp = score_part + (size_t)b * T_DIM;
    float loc[8];
    float m = -1e30f;
#pragma unroll
    for (int i = 0; i < 8; i++) {
        int t = tid + i * 256;
        float s = sp[t] + sp[65536 + t] + sp[131072 + t] + sp[196608 + t];
        loc[i] = s;
        m = fmaxf(m, s);
    }
#pragma unroll
    for (int off = 32; off >= 1; off >>= 1) m = fmaxf(m, __shfl_xor(m, off, 64));
    if (lane == 0) redm[w] = m;
    __syncthreads();
    m = fmaxf(fmaxf(redm[0], redm[1]), fmaxf(redm[2], redm[3]));
    float sum = 0.f;
#pragma unroll
    for (int i = 0; i < 8; i++) {
        loc[i] = __expf(loc[i] - m);
        sum += loc[i];
    }
#pragma unroll
    for (int off = 32; off >= 1; off >>= 1) sum += __shfl_xor(sum, off, 64);
    if (lane == 0) reds[w] = sum;
    __syncthreads();
    sum = reds[0] + reds[1] + reds[2] + reds[3];
    float inv = 1.0f / sum;
    if (tid < 64) {
        int t = tc * 64 + tid;
        float s = sp[t] + sp[65536 + t] + sp[131072 + t] + sp[196608 + t];
        float av = __expf(s - m) * inv;
        aw[(size_t)b * T_DIM + t] = av;
        aw_sh[tid] = av;
    }
    __syncthreads();
    const float4* v4 = reinterpret_cast<const float4*>(
                           values + ((size_t)b * T_DIM + tc * 64) * H_DIM) + tid;
    float4 a = make_float4(0.f, 0.f, 0.f, 0.f);
#pragma unroll 4
    for (int t = 0; t < 64; t++) {
        float wgt = aw_sh[t];
        float4 vv = v4[(size_t)t * (H_DIM / 4)];
        a.x += wgt * vv.x; a.y += wgt * vv.y;
        a.z += wgt * vv.z; a.w += wgt * vv.w;
    }
    float* cp = ctx + (size_t)b * H_DIM + tid * 4;
    atomicAdd(cp + 0, a.x);
    atomicAdd(cp + 1, a.y);
    atomicAdd(cp + 2, a.z);
    atomicAdd(cp + 3, a.w);
}

extern "C" void kernel_launch(void* const* d_in, const int* in_sizes, int n_in,
                              void* d_out, int out_size, void* d_ws, size_t ws_size,
                              hipStream_t stream) {
    const float* query  = (const float*)d_in[0];   // [1][B][H]
    const float* values = (const float*)d_in[1];   // [B][T][H]
    const float* W_w    = (const float*)d_in[2];   // [U][2H]
    const float* W_b    = (const float*)d_in[3];   // [U]
    const float* V_w    = (const float*)d_in[4];   // [1][U]
    // d_in[5] = V_b: uniform score shift, cancels in softmax -> unused.

    float* out = (float*)d_out;
    char* ws = (char*)d_ws;
    float* cvec            = (float*)(ws);                               // 128 KB
    unsigned short* wv     = (unsigned short*)(ws + 131072);             // 2 MB
    float* score_part      = (float*)(ws + 131072 + 2097152);            // 1 MB
    float* ctx = out;                    // [B][H]
    float* aw  = out + B_DIM * H_DIM;    // [B][T]

    prep_wv_kernel<<<U_DIM, 256, 0, stream>>>(W_w, wv);
    prep_c_kernel<<<dim3(U_DIM / 64, B_DIM / 4), 256, 0, stream>>>(query, W_w, W_b, cvec, ctx);
    gemm_score_kernel<<<1024, 512, 0, stream>>>(values, wv, cvec, V_w, score_part);
    ctx_sm_kernel<<<dim3(32, B_DIM), 256, 0, stream>>>(values, score_part, aw, ctx);
}